// Round 3
// baseline (345.417 us; speedup 1.0000x reference)
//
#include <hip/hip_runtime.h>

#define NXD 512
#define NYD 512
#define CD  64
#define NPIX (NXD * NYD)
// Problem constants fixed by the reference: B=4, C=64, NX=NY=512.
//
// Window decomposition (R5, measured via rocprof): harness poisons the 1 GiB
// workspace (166-172 us @ 6.3 TB/s) + 268 MB output (~42 us) INSIDE the timed
// window => ~210 us fixed. Kernel-side share ~= headline - 210. Compare
// kernel dispatch times, not headline dur_us.
//
// Theory ledger:
//   R5 (2 quads/thread, +2^23 apart):   NEUTRAL (289->293) - not latency/MLP.
//   R6 (16-wave channel groups, L1):    NEUTRAL (293->299) - not read traffic.
//   R7 (this): one-shot waves are the last structural difference vs the
//   6.4 TB/s fill (which runs few long-lived grid-stride waves at ~10%
//   occupancy). 262,144 one-shot waves expose per-wave setup + one vmcnt
//   round-trip under full HBM pressure per 1 KB stored. R7: persistent
//   2048x256 grid; each thread holds its pix's 4 winner int4s in REGISTERS
//   (loaded once, 4 independent loads) and sweeps all 32 (b,c) planes at
//   stride 2^19 with 32 back-to-back NT stores. Winner traffic 268->32 MB;
//   feat lines L1-hit across the 8 c-steps sharing a 256B feat row.
//
// Round-3 lesson (measured): per-instruction 16B/lane contiguous stores +
// linear block-order streams are mandatory (R3's per-lane channel sweep
// regressed 79->155 us). R7 keeps both: lanes t..t+63 store consecutive
// out4s every iteration; the active write front is a compact ~2 MB window
// sweeping the output linearly.
//
// Round-4 lesson: __builtin_nontemporal_store needs a NATIVE vector type,
// not HIP's float4 class. Use ext_vector_type(4).

typedef float nfloat4 __attribute__((ext_vector_type(4)));

// Init winner array to -1 (int4 stores). 4 MiB.
__global__ void ppscatter_init_winner(int4* __restrict__ win4, int n_win4) {
    int i = blockIdx.x * blockDim.x + threadIdx.x;
    if (i < n_win4) win4[i] = make_int4(-1, -1, -1, -1);
}

// Last-write-wins vote: max voxel index per flat slot wins (matches numpy
// fancy-assignment last-duplicate-wins; verified absmax=0.0 rounds 1-6).
__global__ void ppscatter_vote(const int* __restrict__ coords, int n,
                               int* __restrict__ winner) {
    int v = blockIdx.x * blockDim.x + threadIdx.x;
    if (v >= n) return;
    int b = coords[3 * v + 0];
    int x = coords[3 * v + 1];
    int y = coords[3 * v + 2];
    atomicMax(&winner[b * NPIX + x * NYD + y], v);
}

// Gather v4: persistent waves, register-held winners, 32 stores/thread.
//   i0 = blockIdx*256 + tid in [0, 2^19); pix = i0[0:15], c0 = i0[16:18].
//   Iteration k in [0,32): out4 index i = i0 + k*2^19
//     -> c = c0 + (k&7)*8, b = k>>3, pix constant.
//   winner[(b<<16)|pix] loaded ONCE per thread for all 4 b (16 VGPRs);
//   steady-state loop is pure {predicated feat loads -> NT store}.
__global__ void __launch_bounds__(256)
ppscatter_gather(const float* __restrict__ feat,
                 const int* __restrict__ winner,
                 nfloat4* __restrict__ out4) {
    int i0  = blockIdx.x * 256 + threadIdx.x;   // [0, 524288)
    int pix = i0 & 0xFFFF;
    int c0  = i0 >> 16;                          // 0..7
    const int4* win4 = (const int4*)winner;

    // Four independent winner loads up front; one wait covers all.
    int4 w0 = win4[pix];
    int4 w1 = win4[(1 << 16) | pix];
    int4 w2 = win4[(2 << 16) | pix];
    int4 w3 = win4[(3 << 16) | pix];

    #pragma unroll
    for (int bb = 0; bb < 4; ++bb) {
        int4 w = (bb == 0) ? w0 : (bb == 1) ? w1 : (bb == 2) ? w2 : w3;
        // Empty fast path: entries are -1 or >=0; AND == -1 iff all empty (~73%).
        bool any = (w.x & w.y & w.z & w.w) != -1;
        #pragma unroll
        for (int cc = 0; cc < 8; ++cc) {
            int c = c0 + (cc << 3);
            nfloat4 val = {0.f, 0.f, 0.f, 0.f};
            if (any) {
                if (w.x >= 0) val.x = feat[(w.x << 6) + c];
                if (w.y >= 0) val.y = feat[(w.y << 6) + c];
                if (w.z >= 0) val.z = feat[(w.z << 6) + c];
                if (w.w >= 0) val.w = feat[(w.w << 6) + c];
            }
            __builtin_nontemporal_store(val, &out4[i0 + ((bb * 8 + cc) << 19)]);
        }
    }
}

extern "C" void kernel_launch(void* const* d_in, const int* in_sizes, int n_in,
                              void* d_out, int out_size, void* d_ws, size_t ws_size,
                              hipStream_t stream) {
    const float* feat  = (const float*)d_in[0];
    const int* coords  = (const int*)d_in[1];

    int n = in_sizes[1] / 3;            // 80000 voxels
    int* winner = (int*)d_ws;           // B*NX*NY ints = 4 MiB scratch

    const int T = 256;
    int B = out_size / (CD * NPIX);     // 4

    int n_win4 = (B * NPIX) / 4;        // 262144
    ppscatter_init_winner<<<(n_win4 + T - 1) / T, T, 0, stream>>>((int4*)winner, n_win4);

    ppscatter_vote<<<(n + T - 1) / T, T, 0, stream>>>(coords, n, winner);

    // 2048 persistent blocks; each thread emits 32 out4s (out_size/4/32 threads).
    int n_thr = out_size / 4 / 32;      // 524288
    ppscatter_gather<<<n_thr / T, T, 0, stream>>>(feat, winner, (nfloat4*)d_out);
}

// Round 4
// 290.488 us; speedup vs baseline: 1.1891x; 1.1891x over previous
//
#include <hip/hip_runtime.h>

#define NXD 512
#define NYD 512
#define CD  64
#define NPIX (NXD * NYD)
// Problem constants fixed by the reference: B=4, C=64, NX=NY=512.
//
// Window decomposition (R5, measured via rocprof): harness poisons the 1 GiB
// workspace (166-172 us @ 6.3 TB/s) + 268 MB output (~42 us) INSIDE the timed
// window => ~210 us fixed. Kernel-side share ~= headline - 210. Compare
// kernel dispatch times, not headline dur_us.
//
// Theory ledger:
//   R5 (2 quads/thread, +2^23 apart):  NEUTRAL (289->293) - not latency/MLP.
//   R6 (16-wave channel groups, L1):   NEUTRAL (293->299) - not read traffic.
//   R7 (persistent, reg winners, x32): REGRESSED (->345) - deep unroll +
//       scattered write front + vmcnt saturation. Reverted.
//   R8 (this): VMEM ADDRESS-PIPE theory. Per 1 KB-store wave, R0 issued
//       1 winner load (16 lines) + 4 exec-masked SCALAR feat gathers
//       (~13 random lines EACH) + 1 store (16 lines) ~= 84 TA cycles/KB;
//       budget at 6.4 TB/s is ~98 cy/KB/CU -> address pipe is the ceiling.
//       R5/R6/R7 never changed instructions-per-byte. R8 amortizes 4x:
//       thread = (b, quad, 4-channel group); ONE winner int4, 4x float4
//       feat loads (16 B/lane, same line count, 4x payload), 4x4 register
//       transpose, 4 NT stores (each still 64x16 B contiguous; 4 parallel
//       linear c-plane streams). ~33 TA cy/KB -> 3x headroom.
//
// Round-3 lesson (measured): per-instruction 16B/lane contiguous stores +
// linear block-order streams are mandatory (R3's per-LANE channel sweep
// regressed 79->155 us). R8 keeps both (4 linear streams, like R5's 2).
//
// Round-4 lesson: __builtin_nontemporal_store needs a NATIVE vector type,
// not HIP's float4 class. Use ext_vector_type(4).

typedef float nfloat4 __attribute__((ext_vector_type(4)));

// Init winner array to -1 (int4 stores). 4 MiB.
__global__ void ppscatter_init_winner(int4* __restrict__ win4, int n_win4) {
    int i = blockIdx.x * blockDim.x + threadIdx.x;
    if (i < n_win4) win4[i] = make_int4(-1, -1, -1, -1);
}

// Last-write-wins vote: max voxel index per flat slot wins (matches numpy
// fancy-assignment last-duplicate-wins; verified absmax=0.0 rounds 1-7).
__global__ void ppscatter_vote(const int* __restrict__ coords, int n,
                               int* __restrict__ winner) {
    int v = blockIdx.x * blockDim.x + threadIdx.x;
    if (v >= n) return;
    int b = coords[3 * v + 0];
    int x = coords[3 * v + 1];
    int y = coords[3 * v + 2];
    atomicMax(&winner[b * NPIX + x * NYD + y], v);
}

// Gather v5: 4-channel groups per thread to amortize VMEM address work.
//   t bits: pix [0:15], cg [16:19], b [20:21]   (4,194,304 threads)
//   Per thread: 1 winner int4; 4 predicated float4 feat loads
//   (feat[w][4cg..4cg+3]); 4x4 transpose; 4 NT stores to channels
//   4cg+j at out4[(b<<22) | ((4cg+j)<<16) | pix].
__global__ void __launch_bounds__(256)
ppscatter_gather(const float* __restrict__ feat,
                 const int* __restrict__ winner,
                 nfloat4* __restrict__ out4) {
    int t   = blockIdx.x * 256 + threadIdx.x;   // [0, 4M)
    int pix = t & 0xFFFF;                       // pixel-quad index
    int cg  = (t >> 16) & 15;                   // channel group (4 channels)
    int b   = t >> 20;                          // batch

    const int4*    win4  = (const int4*)winner;
    const nfloat4* feat4 = (const nfloat4*)feat;
    int4 w = win4[(b << 16) | pix];

    const nfloat4 z = {0.f, 0.f, 0.f, 0.f};
    nfloat4 f0 = z, f1 = z, f2 = z, f3 = z;
    // Empty fast path: entries are -1 or >=0; AND == -1 iff all empty (~74%).
    if ((w.x & w.y & w.z & w.w) != -1) {
        if (w.x >= 0) f0 = feat4[(w.x << 4) + cg];
        if (w.y >= 0) f1 = feat4[(w.y << 4) + cg];
        if (w.z >= 0) f2 = feat4[(w.z << 4) + cg];
        if (w.w >= 0) f3 = feat4[(w.w << 4) + cg];
    }
    // Transpose: v_j[slot] = f_slot[j]  (slot = y position within quad).
    nfloat4 v0 = {f0.x, f1.x, f2.x, f3.x};
    nfloat4 v1 = {f0.y, f1.y, f2.y, f3.y};
    nfloat4 v2 = {f0.z, f1.z, f2.z, f3.z};
    nfloat4 v3 = {f0.w, f1.w, f2.w, f3.w};

    int o = (b << 22) | (cg << 18) | pix;       // channel 4cg+0 plane
    __builtin_nontemporal_store(v0, &out4[o]);
    __builtin_nontemporal_store(v1, &out4[o + (1 << 16)]);
    __builtin_nontemporal_store(v2, &out4[o + (2 << 16)]);
    __builtin_nontemporal_store(v3, &out4[o + (3 << 16)]);
}

extern "C" void kernel_launch(void* const* d_in, const int* in_sizes, int n_in,
                              void* d_out, int out_size, void* d_ws, size_t ws_size,
                              hipStream_t stream) {
    const float* feat  = (const float*)d_in[0];
    const int* coords  = (const int*)d_in[1];

    int n = in_sizes[1] / 3;            // 80000 voxels
    int* winner = (int*)d_ws;           // B*NX*NY ints = 4 MiB scratch

    const int T = 256;
    int B = out_size / (CD * NPIX);     // 4

    int n_win4 = (B * NPIX) / 4;        // 262144
    ppscatter_init_winner<<<(n_win4 + T - 1) / T, T, 0, stream>>>((int4*)winner, n_win4);

    ppscatter_vote<<<(n + T - 1) / T, T, 0, stream>>>(coords, n, winner);

    int n_thr = out_size / 4 / 4;       // 4,194,304 threads (4 out4s each)
    ppscatter_gather<<<n_thr / T, T, 0, stream>>>(feat, winner, (nfloat4*)d_out);
}